// Round 21
// baseline (234.686 us; speedup 1.0000x reference)
//
#include <hip/hip_runtime.h>
#include <cfloat>

// Problem constants (match reference)
constexpr int Bn = 1024, Ln = 1024, Vn = 20, Dn = 128;
constexpr int NJ = 2 * Vn;      // 40 output columns
constexpr int TB = 32;          // steps per block (writeback granularity only)

// v mod 20 for 0 <= v <= ~4000 (magic multiply, exact in this range)
__device__ __forceinline__ int mod20(int v) { return v - 20 * ((v * 205) >> 12); }

// ---- DPP helpers (16-lane row reduce, pure VALU) ----
template<int CTRL>
__device__ __forceinline__ float dpp_mov(float v) {
  return __int_as_float(
      __builtin_amdgcn_update_dpp(0, __float_as_int(v), CTRL, 0xF, 0xF, false));
}
template<int CTRL>
__device__ __forceinline__ float dpp_max(float v) {
  return fmaxf(v, dpp_mov<CTRL>(v));   // fuses to single v_max_f32_dpp (VOP2)
}
// 4-level pure-VOP2 DPP butterfly (R7-proven): each level ONE fused
// v_max_f32_dpp -> depth 4, vs the max3/ror variant's depth 5 (VOP3
// can't take DPP, so each max3 level = mov_dpp + max3 = depth 2).
__device__ __forceinline__ float rowmax16(float v) {
  v = dpp_max<0xB1>(v);    // quad_perm xor1
  v = dpp_max<0x4E>(v);    // quad_perm xor2
  v = dpp_max<0x141>(v);   // row_half_mirror
  v = dpp_max<0x140>(v);   // row_mirror
  return v;
}

// inv mod 20 packed table: 5-bit entries for odd s, indexed by s>>1
constexpr unsigned long long INVT =
    (1ull << 0) | (7ull << 5) | (0ull << 10) | (3ull << 15) | (9ull << 20) |
    (11ull << 25) | (17ull << 30) | (0ull << 35) | (13ull << 40) | (19ull << 45);

__global__ __launch_bounds__(64, 1) void daf_chain(
    const float* __restrict__ x, const float* __restrict__ emb,
    const float* __restrict__ W, const float* __restrict__ bvec,
    float* __restrict__ out)
{
  __shared__ alignas(8)  float  ewf32[Vn * 64];   //  5120 B: EW f32 {lo,hi}/pos
  __shared__ alignas(16) unsigned char aidx[Ln];  //  1024 B: token index per step
  // total 6144 B

  const int lane = threadIdx.x;
  const int batch = blockIdx.x;
  const int p   = lane & 15;          // position within row
  const int rB  = (lane >> 4) & 1;    // 0 = loc row, 1 = scale row
  const int pos = lane & 31;          // row-pair position (lanes 32..63 mirror)

  // ---- Prologue: extract token indices (coalesced float4) ----
  // Single-wave block: LDS ops complete in-order within the wave -> no barriers.
  const float4* xb4 = (const float4*)(x + (size_t)batch * Ln * Vn);
  for (int i = lane; i < Ln * (Vn / 4); i += 64) {
    const float4 v = xb4[i];
    const int row = i / 5, cb = (i % 5) * 4;
    if (v.x > 0.5f) aidx[row] = (unsigned char)(cb + 0);
    if (v.y > 0.5f) aidx[row] = (unsigned char)(cb + 1);
    if (v.z > 0.5f) aidx[row] = (unsigned char)(cb + 2);
    if (v.w > 0.5f) aidx[row] = (unsigned char)(cb + 3);
  }

  // ---- EW[k][j] = f64 dot(emb[k], W[:,j]) from GLOBAL (L1/L2-hot, prologue
  //      only); stored f32, distributed layout (R7). Same values the passing
  //      R18-R20 chains consumed. ----
  for (int e = lane; e < Vn * NJ; e += 64) {
    const int k = e / NJ, j = e - k * NJ;
    double acc = 0.0;
#pragma unroll 4
    for (int d = 0; d < Dn; ++d)
      acc = __builtin_fma((double)emb[k * Dn + d], (double)W[d * NJ + j], acc);
    int q, slot;
    if (j < 16)      { q = j;             slot = 0; }
    else if (j < 20) { q = j - 16;        slot = 1; }
    else if (j < 36) { q = 16 + (j - 20); slot = 0; }
    else             { q = 16 + (j - 36); slot = 1; }
    ewf32[k * 64 + q * 2 + slot] = (float)acc;
  }
  if ((pos & 15) >= 4) {  // zero undefined hi slots so (-FLT_MAX += 0) stays put
    for (int k = 0; k < Vn; ++k) ewf32[k * 64 + pos * 2 + 1] = 0.0f;
  }

  // ---- init nets (distributed, f32): exact b (state 0) ----
  const int jlo = rB ? (20 + p) : p;
  float nlo = bvec[jlo];
  float nhi = (p < 4) ? bvec[jlo + 16] : -FLT_MAX;

  float* outb = out + (size_t)batch * Ln * Vn;

  for (int tb = 0; tb < Ln / TB; ++tb) {
    // token prefetch: 32 tokens -> 8 SGPRs (two broadcast b128 reads)
    const uint4 tva = *(const uint4*)(aidx + tb * TB);
    const uint4 tvb = *(const uint4*)(aidx + tb * TB + 16);
    const int tk0 = __builtin_amdgcn_readfirstlane((int)tva.x);
    const int tk1 = __builtin_amdgcn_readfirstlane((int)tva.y);
    const int tk2 = __builtin_amdgcn_readfirstlane((int)tva.z);
    const int tk3 = __builtin_amdgcn_readfirstlane((int)tva.w);
    const int tk4 = __builtin_amdgcn_readfirstlane((int)tvb.x);
    const int tk5 = __builtin_amdgcn_readfirstlane((int)tvb.y);
    const int tk6 = __builtin_amdgcn_readfirstlane((int)tvb.z);
    const int tk7 = __builtin_amdgcn_readfirstlane((int)tvb.w);

    unsigned long long q0 = 0ull, q1 = 0ull, q2 = 0ull;  // 32 x 5-bit oidx

#pragma unroll
    for (int u = 0; u < TB; ++u) {
      const int tw = (u < 4) ? tk0 : (u < 8) ? tk1 : (u < 12) ? tk2 :
                     (u < 16) ? tk3 : (u < 20) ? tk4 : (u < 24) ? tk5 :
                     (u < 28) ? tk6 : tk7;
      const int as20 = ((tw >> ((u & 3) * 8)) & 0xFF) + Vn;  // SALU, off-chain

      // ---- argmax on f32 nets: fmax + 4-level fused-DPP butterfly ----
      float m = fmaxf(nlo, nhi);
      m = rowmax16(m);
      const unsigned long long bLo = __ballot(nlo == m);
      const unsigned long long bHi = __ballot(nhi == m);
      const unsigned wLoc = ((unsigned)bLo & 0xFFFFu) | (((unsigned)bHi & 0xFu) << 16);
      const unsigned wScl = ((unsigned)(bLo >> 16) & 0xFFFFu) |
                            (((unsigned)(bHi >> 16) & 0xFu) << 16);
      const int locI = (int)__builtin_ctz(wLoc);   // first-max = smallest j
      const int sclI = (int)__builtin_ctz(wScl);

      // oidx = (inv20(scale) * (a + 20 - loc)) mod 20  (pure SALU, uniform)
      const int r = as20 - locI;                   // in [1, 39]
      const int inv = (sclI & 1) ? (int)((INVT >> ((sclI >> 1) * 5)) & 31ull) : 0;
      const int oidx = mod20(inv * r);             // inv*r <= 741, magic exact

      // ---- CHAIN: f32 update, ds_read_b64 (stride 8B -> 2-way = free);
      //      the ONLY LDS op in the steady loop ----
      const float2 e32 = *(const float2*)(ewf32 + oidx * 64 + pos * 2);
      nlo += e32.x; nhi += e32.y;

      // pack oidx (SALU, off-chain): 12 / 12 / 8 per u64
      if (u < 12)      q0 |= (unsigned long long)(unsigned)oidx << (5 * u);
      else if (u < 24) q1 |= (unsigned long long)(unsigned)oidx << (5 * (u - 12));
      else             q2 |= (unsigned long long)(unsigned)oidx << (5 * (u - 24));
    }

    // ---- batched one-hot writeback: 640 floats, coalesced (10/lane) ----
    {
      const int rl   = lane >> 1;               // step 0..31 of the block
      const int half = lane & 1;                // cols 0-9 or 10-19
      const unsigned long long w = (rl < 12) ? q0 : (rl < 24) ? q1 : q2;
      const int sh = 5 * ((rl < 12) ? rl : (rl < 24) ? (rl - 12) : (rl - 24));
      const int od = (int)((w >> sh) & 31ull);
      float* ob = outb + (size_t)tb * (TB * Vn) + rl * Vn + half * 10;
      const int c0 = half * 10;
#pragma unroll
      for (int c = 0; c < 10; ++c)
        ob[c] = (c0 + c == od) ? 1.0f : 0.0f;
    }
  }
}

extern "C" void kernel_launch(void* const* d_in, const int* in_sizes, int n_in,
                              void* d_out, int out_size, void* d_ws, size_t ws_size,
                              hipStream_t stream) {
  const float* x   = (const float*)d_in[0];
  const float* emb = (const float*)d_in[1];
  const float* W   = (const float*)d_in[2];
  const float* b   = (const float*)d_in[3];
  float* out = (float*)d_out;
  hipLaunchKernelGGL(daf_chain, dim3(Bn), dim3(64), 0, stream,
                     x, emb, W, b, out);
}

// Round 22
// 226.316 us; speedup vs baseline: 1.0370x; 1.0370x over previous
//
#include <hip/hip_runtime.h>
#include <cfloat>

// Problem constants (match reference)
constexpr int Bn = 1024, Ln = 1024, Vn = 20, Dn = 128;
constexpr int NJ = 2 * Vn;      // 40 output columns
constexpr int TB = 32;          // steps per block (writeback granularity only)

// v mod 20 for 0 <= v <= ~4000 (magic multiply, exact in this range)
__device__ __forceinline__ int mod20(int v) { return v - 20 * ((v * 205) >> 12); }

// ---- DPP helpers (16-lane row reduce, pure VALU) ----
template<int CTRL>
__device__ __forceinline__ float dpp_mov(float v) {
  return __int_as_float(
      __builtin_amdgcn_update_dpp(0, __float_as_int(v), CTRL, 0xF, 0xF, false));
}
template<int CTRL>
__device__ __forceinline__ float dpp_max(float v) {
  return fmaxf(v, dpp_mov<CTRL>(v));
}
__device__ __forceinline__ float max3f(float a, float b, float c) {
  return fmaxf(fmaxf(a, b), c);   // fuses to v_max3_f32
}
// 3-level reduce (measured-best, R13/R20): pair max, then max3 over rotations
// {2,4} and {6,12}. Beats the 4-level VOP2 butterfly by ~19 cyc/step (R21).
__device__ __forceinline__ float rowmax16(float v) {
  const float a1 = dpp_max<0xB1>(v);                               // pair max
  const float t2 = max3f(a1, dpp_mov<0x122>(a1), dpp_mov<0x124>(a1));
  return max3f(t2, dpp_mov<0x126>(t2), dpp_mov<0x12C>(t2));
}

// inv mod 20 packed table: 5-bit entries for odd s, indexed by s>>1
constexpr unsigned long long INVT =
    (1ull << 0) | (7ull << 5) | (0ull << 10) | (3ull << 15) | (9ull << 20) |
    (11ull << 25) | (17ull << 30) | (0ull << 35) | (13ull << 40) | (19ull << 45);

__global__ __launch_bounds__(64, 1) void daf_chain(
    const float* __restrict__ x, const float* __restrict__ emb,
    const float* __restrict__ W, const float* __restrict__ bvec,
    float* __restrict__ out)
{
  __shared__ alignas(8)  float  ewf32[Vn * 64];   //  5120 B: EW f32 {lo,hi}/pos
  __shared__ alignas(16) unsigned char aidx[Ln];  //  1024 B: token index per step
  // total 6144 B

  const int lane = threadIdx.x;
  const int batch = blockIdx.x;
  const int p   = lane & 15;          // position within row
  const int rB  = (lane >> 4) & 1;    // 0 = loc row, 1 = scale row
  const int pos = lane & 31;          // row-pair position (lanes 32..63 mirror)

  // ---- Prologue: extract token indices (coalesced float4) ----
  // Single-wave block: LDS ops complete in-order within the wave -> no barriers.
  const float4* xb4 = (const float4*)(x + (size_t)batch * Ln * Vn);
  for (int i = lane; i < Ln * (Vn / 4); i += 64) {
    const float4 v = xb4[i];
    const int row = i / 5, cb = (i % 5) * 4;
    if (v.x > 0.5f) aidx[row] = (unsigned char)(cb + 0);
    if (v.y > 0.5f) aidx[row] = (unsigned char)(cb + 1);
    if (v.z > 0.5f) aidx[row] = (unsigned char)(cb + 2);
    if (v.w > 0.5f) aidx[row] = (unsigned char)(cb + 3);
  }

  // ---- EW[k][j] = f64 dot(emb[k], W[:,j]) from GLOBAL (L1/L2-hot, prologue
  //      only); stored f32, distributed layout (R7). ----
  for (int e = lane; e < Vn * NJ; e += 64) {
    const int k = e / NJ, j = e - k * NJ;
    double acc = 0.0;
#pragma unroll 4
    for (int d = 0; d < Dn; ++d)
      acc = __builtin_fma((double)emb[k * Dn + d], (double)W[d * NJ + j], acc);
    int q, slot;
    if (j < 16)      { q = j;             slot = 0; }
    else if (j < 20) { q = j - 16;        slot = 1; }
    else if (j < 36) { q = 16 + (j - 20); slot = 0; }
    else             { q = 16 + (j - 36); slot = 1; }
    ewf32[k * 64 + q * 2 + slot] = (float)acc;
  }
  if ((pos & 15) >= 4) {  // zero undefined hi slots so (-FLT_MAX += 0) stays put
    for (int k = 0; k < Vn; ++k) ewf32[k * 64 + pos * 2 + 1] = 0.0f;
  }

  // ---- init nets (distributed, f32): exact b (state 0) ----
  const int jlo = rB ? (20 + p) : p;
  float nlo = bvec[jlo];
  float nhi = (p < 4) ? bvec[jlo + 16] : -FLT_MAX;

  float* outb = out + (size_t)batch * Ln * Vn;

  for (int tb = 0; tb < Ln / TB; ++tb) {
    // token prefetch: 32 tokens -> 8 SGPRs (two broadcast b128 reads)
    const uint4 tva = *(const uint4*)(aidx + tb * TB);
    const uint4 tvb = *(const uint4*)(aidx + tb * TB + 16);
    const int tk0 = __builtin_amdgcn_readfirstlane((int)tva.x);
    const int tk1 = __builtin_amdgcn_readfirstlane((int)tva.y);
    const int tk2 = __builtin_amdgcn_readfirstlane((int)tva.z);
    const int tk3 = __builtin_amdgcn_readfirstlane((int)tva.w);
    const int tk4 = __builtin_amdgcn_readfirstlane((int)tvb.x);
    const int tk5 = __builtin_amdgcn_readfirstlane((int)tvb.y);
    const int tk6 = __builtin_amdgcn_readfirstlane((int)tvb.z);
    const int tk7 = __builtin_amdgcn_readfirstlane((int)tvb.w);

    unsigned long long q0 = 0ull, q1 = 0ull, q2 = 0ull;  // 32 x 5-bit oidx

#pragma unroll
    for (int u = 0; u < TB; ++u) {
      const int tw = (u < 4) ? tk0 : (u < 8) ? tk1 : (u < 12) ? tk2 :
                     (u < 16) ? tk3 : (u < 20) ? tk4 : (u < 24) ? tk5 :
                     (u < 28) ? tk6 : tk7;
      const int as20 = ((tw >> ((u & 3) * 8)) & 0xFF) + Vn;  // SALU, off-chain

      // ---- argmax on f32 nets ----
      float m = fmaxf(nlo, nhi);
      m = rowmax16(m);
      const unsigned long long bLo = __ballot(nlo == m);
      const unsigned long long bHi = __ballot(nhi == m);
      const unsigned wLoc = ((unsigned)bLo & 0xFFFFu) | (((unsigned)bHi & 0xFu) << 16);
      const unsigned wScl = ((unsigned)(bLo >> 16) & 0xFFFFu) |
                            (((unsigned)(bHi >> 16) & 0xFu) << 16);
      const int locI = (int)__builtin_ctz(wLoc);   // first-max = smallest j
      const int sclI = (int)__builtin_ctz(wScl);

      // oidx = (inv20(scale) * (a + 20 - loc)) mod 20  (pure SALU, uniform)
      const int r = as20 - locI;                   // in [1, 39]
      const int inv = (sclI & 1) ? (int)((INVT >> ((sclI >> 1) * 5)) & 31ull) : 0;
      const int oidx = mod20(inv * r);             // inv*r <= 741, magic exact

      // ---- CHAIN: f32 update, ds_read_b64 (stride 8B -> 2-way = free);
      //      the ONLY LDS op in the steady loop. No shadow, no anchor. ----
      const float2 e32 = *(const float2*)(ewf32 + oidx * 64 + pos * 2);
      nlo += e32.x; nhi += e32.y;

      // pack oidx (SALU, off-chain): 12 / 12 / 8 per u64
      if (u < 12)      q0 |= (unsigned long long)(unsigned)oidx << (5 * u);
      else if (u < 24) q1 |= (unsigned long long)(unsigned)oidx << (5 * (u - 12));
      else             q2 |= (unsigned long long)(unsigned)oidx << (5 * (u - 24));
    }

    // ---- batched one-hot writeback: 640 floats, coalesced (10/lane) ----
    {
      const int rl   = lane >> 1;               // step 0..31 of the block
      const int half = lane & 1;                // cols 0-9 or 10-19
      const unsigned long long w = (rl < 12) ? q0 : (rl < 24) ? q1 : q2;
      const int sh = 5 * ((rl < 12) ? rl : (rl < 24) ? (rl - 12) : (rl - 24));
      const int od = (int)((w >> sh) & 31ull);
      float* ob = outb + (size_t)tb * (TB * Vn) + rl * Vn + half * 10;
      const int c0 = half * 10;
#pragma unroll
      for (int c = 0; c < 10; ++c)
        ob[c] = (c0 + c == od) ? 1.0f : 0.0f;
    }
  }
}

extern "C" void kernel_launch(void* const* d_in, const int* in_sizes, int n_in,
                              void* d_out, int out_size, void* d_ws, size_t ws_size,
                              hipStream_t stream) {
  const float* x   = (const float*)d_in[0];
  const float* emb = (const float*)d_in[1];
  const float* W   = (const float*)d_in[2];
  const float* b   = (const float*)d_in[3];
  float* out = (float*)d_out;
  hipLaunchKernelGGL(daf_chain, dim3(Bn), dim3(64), 0, stream,
                     x, emb, W, b, out);
}